// Round 13
// baseline (481.625 us; speedup 1.0000x reference)
//
#include <hip/hip_runtime.h>
#include <cstdint>
#include <cstddef>

#define TSEQ 4096
#define BATCH 2
#define DIM 256
#define NHEAD 8
#define HDIM 32
#define NLAYER 4
#define FFDIM 1024
#define SPLITN 2048
#define MROWS (BATCH * TSEQ)   // 8192

// (1/sqrt(HD)) * log2(e)  -- folded into q at the QKV epilogue so softmax uses exp2 directly
#define QSCALE 0.2550784545f

typedef __attribute__((ext_vector_type(4))) float f32x4;
typedef __attribute__((ext_vector_type(8))) short bf16x8;

__device__ __forceinline__ short f2bf(float f) {
  union { float f; uint32_t u; } v; v.f = f;
  uint32_t r = v.u + 0x7fffu + ((v.u >> 16) & 1u);
  return (short)(r >> 16);
}

__device__ __forceinline__ float bf2f(short s) {
  union { uint32_t u; float f; } v; v.u = ((uint32_t)(uint16_t)s) << 16;
  return v.f;
}

__device__ __forceinline__ float fast_exp2(float x) {
#if __has_builtin(__builtin_amdgcn_exp2f)
  return __builtin_amdgcn_exp2f(x);
#else
  float r;
  asm volatile("v_exp_f32 %0, %1\n\ts_nop 1" : "=v"(r) : "v"(x));
  return r;
#endif
}

// pack two fp32 -> two bf16 (round-half-up; 3 VALU ops; verified rounds 0-5, 8-11)
__device__ __forceinline__ uint32_t pack2bf(float a, float b) {
  union { float f; uint32_t u; } ua, ub; ua.f = a; ub.f = b;
  return ((ua.u + 0x8000u) >> 16) | ((ub.u + 0x8000u) & 0xffff0000u);
}

__device__ __forceinline__ bf16x8 mk8(uint32_t a, uint32_t b, uint32_t c, uint32_t d) {
  union { uint32_t u[4]; bf16x8 v; } x; x.u[0] = a; x.u[1] = b; x.u[2] = c; x.u[3] = d;
  return x.v;
}

__device__ __forceinline__ float gelu_f(float x) {
  float u = 0.7978845608f * x * (1.0f + 0.044715f * x * x);
  u = fminf(fmaxf(u, -20.f), 20.f);
  float e = fast_exp2(2.885390082f * u);   // exp(2u)
  float t = (e - 1.0f) / (e + 1.0f);
  return 0.5f * x * (1.0f + t);
}

#define AS1 __attribute__((address_space(1)))
#define AS3 __attribute__((address_space(3)))
__device__ __forceinline__ void gload16(const void* g, void* l) {
  __builtin_amdgcn_global_load_lds((AS1 void*)g, (AS3 void*)l, 16, 0, 0);
}

// ---------------------------------------------------------------- weight prep
__global__ __launch_bounds__(256) void prep_w(
    const float* __restrict__ Wq, const float* __restrict__ Wk,
    const float* __restrict__ Wv, const float* __restrict__ Wo,
    const float* __restrict__ W1, const float* __restrict__ W2,
    short* __restrict__ qkvT, short* __restrict__ woT,
    short* __restrict__ w1T, short* __restrict__ w2T)
{
  const int NQKV = NLAYER * 768 * DIM;
  const int NO   = NLAYER * DIM * DIM;
  const int NF   = NLAYER * FFDIM * DIM;
  const int total = NQKV + NO + 2 * NF;
  for (int idx = blockIdx.x * 256 + threadIdx.x; idx < total; idx += gridDim.x * 256) {
    if (idx < NQKV) {                       // qkvT[l][n:768][k:256]
      const int l = idx / (768 * DIM);
      const int rem = idx - l * 768 * DIM;
      const int n = rem >> 8, k = rem & 255;
      const float* src = (n < 256) ? Wq : ((n < 512) ? Wk : Wv);
      qkvT[idx] = f2bf(src[((size_t)l * DIM + k) * DIM + (n & 255)]);
    } else if (idx < NQKV + NO) {           // woT[l][n:256][k:256]
      const int j = idx - NQKV;
      const int l = j >> 16;
      const int rem = j & 65535;
      const int n = rem >> 8, k = rem & 255;
      woT[j] = f2bf(Wo[((size_t)l * DIM + k) * DIM + n]);
    } else if (idx < NQKV + NO + NF) {      // w1T[l][n:1024][k:256]
      const int j = idx - NQKV - NO;
      const int l = j >> 18;
      const int rem = j & 262143;
      const int n = rem >> 8, k = rem & 255;
      w1T[j] = f2bf(W1[((size_t)l * DIM + k) * FFDIM + n]);
    } else {                                // w2T[l][n:256][k:1024]
      const int j = idx - NQKV - NO - NF;
      const int l = j >> 18;
      const int rem = j & 262143;
      const int n = rem >> 10, k = rem & 1023;
      w2T[j] = f2bf(W2[((size_t)l * FFDIM + k) * DIM + n]);
    }
  }
}

// ------------------------------------------------------------------- x prep
__global__ __launch_bounds__(256) void prep_x(
    const float* __restrict__ rows, const float* __restrict__ tte,
    float* __restrict__ xf, short* __restrict__ xb)
{
  const size_t idx = (size_t)blockIdx.x * 256 + threadIdx.x;  // float4 index
  float4 v = ((const float4*)rows)[idx];
  const size_t e = idx * 4;
  const int m = (int)(e >> 8);
  const int d = (int)(e & 255);
  const int t = m & (TSEQ - 1);
  const int bb = m >> 12;
  if (t < SPLITN) {
    const float4 a = ((const float4*)tte)[((size_t)bb * SPLITN + t) * (DIM / 4) + (d >> 2)];
    v.x += a.x; v.y += a.y; v.z += a.z; v.w += a.w;
  }
  ((float4*)xf)[idx] = v;
  short4 pk; pk.x = f2bf(v.x); pk.y = f2bf(v.y); pk.z = f2bf(v.z); pk.w = f2bf(v.w);
  ((short4*)xb)[idx] = pk;
}

// ---------------------------------------------------------------------- GEMM
// (m97 pattern + T2 both-sides swizzle; round-1/5 config — best measured)
// EPI: 1=qkv (+bias, q scaled, bf16)  3=gelu bf16.
#define GBM 128
#define GBN 64
#define GBK 64

template<int EPI>
__global__ __launch_bounds__(256, 4) void gemm_bt(
    const short* __restrict__ A, const short* __restrict__ BT,
    const float* __restrict__ bias0, const float* __restrict__ bias1,
    const float* __restrict__ bias2, void* __restrict__ Cout,
    int M, int N, int K)
{
  __shared__ short As[GBM * GBK];
  __shared__ short Bs[GBN * GBK];
  const int tid = threadIdx.x;
  const int lane = tid & 63;
  const int wave = tid >> 6;
  const int wm = wave & 1, wn = wave >> 1;
  const int col = lane & 15, quad = lane >> 4;

  const short* Ab = A + (size_t)blockIdx.x * GBM * K;
  const short* Bb = BT + (size_t)blockIdx.y * GBN * K;

  const f32x4 fz = {0.f, 0.f, 0.f, 0.f};
  f32x4 acc[4][2];
#pragma unroll
  for (int i = 0; i < 4; ++i)
#pragma unroll
    for (int j = 0; j < 2; ++j) acc[i][j] = fz;

  for (int k0 = 0; k0 < K; k0 += GBK) {
#pragma unroll
    for (int p = 0; p < 4; ++p) {
      const int i = p * 256 + tid;
      const int r = i >> 3, g = i & 7;
      gload16(Ab + (size_t)r * K + k0 + ((g ^ (r & 7)) * 8), &As[i * 8]);
    }
#pragma unroll
    for (int p = 0; p < 2; ++p) {
      const int i = p * 256 + tid;
      const int r = i >> 3, g = i & 7;
      gload16(Bb + (size_t)r * K + k0 + ((g ^ (r & 7)) * 8), &Bs[i * 8]);
    }
    __syncthreads();
#pragma unroll
    for (int ks = 0; ks < GBK; ks += 32) {
      bf16x8 af[4], bfr[2];
      const int gq = (ks >> 3) + quad;
#pragma unroll
      for (int tm = 0; tm < 4; ++tm) {
        const int row = wm * 64 + tm * 16 + col;
        af[tm] = *(const bf16x8*)&As[row * GBK + ((gq ^ (row & 7)) * 8)];
      }
#pragma unroll
      for (int tn = 0; tn < 2; ++tn) {
        const int row = wn * 32 + tn * 16 + col;
        bfr[tn] = *(const bf16x8*)&Bs[row * GBK + ((gq ^ (row & 7)) * 8)];
      }
#pragma unroll
      for (int tm = 0; tm < 4; ++tm)
#pragma unroll
        for (int tn = 0; tn < 2; ++tn)
          acc[tm][tn] = __builtin_amdgcn_mfma_f32_16x16x32_bf16(af[tm], bfr[tn], acc[tm][tn], 0, 0, 0);
    }
    __syncthreads();
  }

#pragma unroll
  for (int tm = 0; tm < 4; ++tm) {
    const int mbase = blockIdx.x * GBM + wm * 64 + tm * 16 + quad * 4;
#pragma unroll
    for (int tn = 0; tn < 2; ++tn) {
      const int n = blockIdx.y * GBN + wn * 32 + tn * 16 + col;
      float bv;
      if (EPI == 1) bv = (n < 256) ? bias0[n] : ((n < 512) ? bias1[n - 256] : bias2[n - 512]);
      else          bv = bias0[n];
#pragma unroll
      for (int r = 0; r < 4; ++r) {
        float v = acc[tm][tn][r] + bv;
        size_t off = (size_t)(mbase + r) * N + n;
        if (EPI == 1) {
          if (n < 256) v *= QSCALE;
          ((short*)Cout)[off] = f2bf(v);
        } else {
          ((short*)Cout)[off] = f2bf(gelu_f(v));
        }
      }
    }
  }
}

// ------------------------------------------------ GEMM + residual + LN fused
// C = A@BT^T + bias (N=256 full), out = LN(xres + C)*gs + gb.
// M-tile 16, grid 512 = 2 blocks/CU (round-11 win: was 1 wave/SIMD at M32).
__global__ __launch_bounds__(256, 2) void gemm_ln(
    const short* __restrict__ A,
    const short* __restrict__ BT, const float* __restrict__ bias,
    const float* __restrict__ xres,
    const float* __restrict__ gs, const float* __restrict__ gb,
    float* __restrict__ xoutf, short* __restrict__ xoutb, int K)
{
  __shared__ short As[2][16 * 64];
  __shared__ short Bs[2][256 * 64];
  __shared__ float ssum[4][16], ssq[4][16];
  const int tid = threadIdx.x;
  const int lane = tid & 63;
  const int wave = tid >> 6;
  const int col = lane & 15, quad = lane >> 4;
  const int m0 = blockIdx.x * 16;

  const f32x4 fz = {0.f, 0.f, 0.f, 0.f};
  f32x4 acc[4];
#pragma unroll
  for (int j = 0; j < 4; ++j) acc[j] = fz;

  // per-thread A-staging coords: 128 granules (16 rows x 8), threads <128
  const int arow = (tid >> 3) & 15;   // 0..15
  const int agr  = tid & 7;           // granule (8 cols)
  const int grow = m0 + arow;
  const int asw  = (agr ^ (arow & 7)) * 8;   // swizzled source granule (elems)

#define STAGE_B(k0_, buf_) do {                                              \
    _Pragma("unroll")                                                        \
    for (int p_ = 0; p_ < 8; ++p_) {                                         \
      const int i_ = p_ * 256 + tid;                                         \
      const int r_ = i_ >> 3, g_ = i_ & 7;                                   \
      gload16(BT + (size_t)r_ * K + (k0_) + ((g_ ^ (r_ & 7)) * 8),           \
              &Bs[buf_][i_ * 8]);                                            \
    } } while (0)

#define STAGE_A(k0_, buf_) do {                                              \
    if (tid < 128)                                                           \
      gload16(A + (size_t)grow * K + (k0_) + asw, &As[buf_][tid * 8]);       \
    } while (0)

  const int NT = K / 64;
  STAGE_B(0, 0);
  STAGE_A(0, 0);
  __syncthreads();

  int cur = 0;
  for (int t = 0; t < NT; ++t) {
    if (t + 1 < NT) {
      STAGE_B((t + 1) * 64, cur ^ 1);
      STAGE_A((t + 1) * 64, cur ^ 1);
    }
#pragma unroll
    for (int ks = 0; ks < 64; ks += 32) {
      bf16x8 af, bfr[4];
      const int gq = (ks >> 3) + quad;
      af = *(const bf16x8*)&As[cur][col * 64 + ((gq ^ (col & 7)) * 8)];
#pragma unroll
      for (int tn = 0; tn < 4; ++tn) {
        const int row = wave * 64 + tn * 16 + col;
        bfr[tn] = *(const bf16x8*)&Bs[cur][row * 64 + ((gq ^ (row & 7)) * 8)];
      }
#pragma unroll
      for (int tn = 0; tn < 4; ++tn)
        acc[tn] = __builtin_amdgcn_mfma_f32_16x16x32_bf16(af, bfr[tn], acc[tn], 0, 0, 0);
    }
    __syncthreads();
    cur ^= 1;
  }
#undef STAGE_B
#undef STAGE_A

  // v = acc + bias + residual
  const float* resb = xres + (size_t)m0 * DIM;
#pragma unroll
  for (int tn = 0; tn < 4; ++tn) {
    const int n = wave * 64 + tn * 16 + col;
    const float bv = bias[n];
#pragma unroll
    for (int r = 0; r < 4; ++r) {
      const int row = quad * 4 + r;
      acc[tn][r] += bv + resb[(size_t)row * DIM + n];
    }
  }

  // per-row LN stats (rows 0..15)
#pragma unroll
  for (int r = 0; r < 4; ++r) {
    float s = 0.f, q = 0.f;
#pragma unroll
    for (int tn = 0; tn < 4; ++tn) { const float v = acc[tn][r]; s += v; q += v * v; }
    s += __shfl_xor(s, 1); q += __shfl_xor(q, 1);
    s += __shfl_xor(s, 2); q += __shfl_xor(q, 2);
    s += __shfl_xor(s, 4); q += __shfl_xor(q, 4);
    s += __shfl_xor(s, 8); q += __shfl_xor(q, 8);
    if (col == 0) { const int row = quad * 4 + r; ssum[wave][row] = s; ssq[wave][row] = q; }
  }
  __syncthreads();
  if (tid < 16) {
    const float S = ssum[0][tid] + ssum[1][tid] + ssum[2][tid] + ssum[3][tid];
    const float Q = ssq[0][tid] + ssq[1][tid] + ssq[2][tid] + ssq[3][tid];
    const float mu = S * (1.0f / DIM);
    const float var = Q * (1.0f / DIM) - mu * mu;
    ssum[0][tid] = mu;
    ssq[0][tid] = rsqrtf(var + 1e-5f);
  }
  __syncthreads();

#pragma unroll
  for (int tn = 0; tn < 4; ++tn) {
    const int n = wave * 64 + tn * 16 + col;
    const float g = gs[n], bb = gb[n];
#pragma unroll
    for (int r = 0; r < 4; ++r) {
      const int row = quad * 4 + r;
      const float out = (acc[tn][r] - ssum[0][row]) * ssq[0][row] * g + bb;
      xoutf[(size_t)(m0 + row) * DIM + n] = out;
      xoutb[(size_t)(m0 + row) * DIM + n] = f2bf(out);
    }
  }
}

// ----------------------------------------------------------------- attention
// Round-5 geometry (128q/block, 4 waves x 32q, AKT=64, NKT=32) + cross-tile
// S/PV software pipeline (round-7 structure, audited; the rounds-6/7 failures
// shared exactly one datapath difference from the verified kernel: the
// v_cvt_pk_bf16_f32 inline asm.  This retry uses the VERIFIED pack2bf —
// single-variable change):
//   iter t: issue K(t+2) DMA -> Kb[t&1]; S(t+1) from Kb[(t+1)&1] in parallel
//   with PV(t) from Vb[t%3]; write V(t+2) regs -> Vb[(t+2)%3]; barrier.
// S's exp2/pack chain (VALU/trans) overlaps PV's MFMAs (matrix pipe).
// Prologue S(0) is barrier-separated from iter-0's K(2) DMA into Kbuf[0].
// V uses the PERMUTED key order (contraction invariant under a key
// permutation applied to both P and V):
//   slot k = quad*8+e  <->  key = (2*kh + (e>>2))*16 + quad*4 + (e&3)
// so P fragments are built entirely in registers after exp2 (no LDS P).
// Block owns the full softmax denominator -> normalize in-register, write
// bf16 O directly.  Diagonal self-key handled elementwise.
#define AKT 64
#define NKT (SPLITN / AKT)   // 32

__global__ __launch_bounds__(256, 2) void attn_kernel(
    const short* __restrict__ qkv, short* __restrict__ ob)
{
  __shared__ short Kbuf[2][AKT * HDIM];   // [part(4)][key(64)][8]
  __shared__ short Vbuf[3][HDIM * AKT];   // [hd][slot-swz], slot = permuted key
  __shared__ float Pdiag[4][16];

  const int tid = threadIdx.x;
  const int lane = tid & 63;
  const int wave = tid >> 6;
  const int col = lane & 15, quad = lane >> 4;
  const int bh = blockIdx.y;
  const int b = bh >> 3, h = bh & 7;
  const int q0 = blockIdx.x * 128 + wave * 32;

  const short* qbase = qkv + (size_t)b * TSEQ * 768 + h * HDIM;
  const short* kbase = qbase + 256;
  const short* vcol  = qbase + 512;

  // K staging: thread -> key tid&63, part tid>>6 (gload16, lane-linear dest)
  const short* ksrc = kbase + (size_t)(tid & 63) * 768 + (tid >> 6) * 8;
  // V staging: thread -> key tid&63, hd-group tid>>6 (8 hd, 16B contiguous).
  const int vkey = tid & 63, vhg = tid >> 6;
  const int vs = vkey >> 4, vqd = (vkey >> 2) & 3, vrr = vkey & 3;
  const int vpos = (vs >> 1) * 32 + vqd * 8 + (vs & 1) * 4 + vrr;
  const int vgs = vpos >> 3, vo8 = vpos & 7;   // granule slot, in-granule offset
  const short* vsrc = vcol + (size_t)vkey * 768 + vhg * 8;

  const bf16x8 qf0 = *(const bf16x8*)(qbase + (size_t)(q0 + col) * 768 + quad * 8);
  const bf16x8 qf1 = *(const bf16x8*)(qbase + (size_t)(q0 + 16 + col) * 768 + quad * 8);

  bf16x8 ones;
#pragma unroll
  for (int i = 0; i < 8; ++i) ones[i] = (short)0x3F80;

  const f32x4 fz = {0.f, 0.f, 0.f, 0.f};
  f32x4 o[2][2] = {{fz, fz}, {fz, fz}};
  f32x4 lacc[2] = {fz, fz};

#define S_PHASE(KB, PN0, PN1) do {                                           \
    _Pragma("unroll")                                                        \
    for (int st = 0; st < 4; ++st) {                                         \
      const bf16x8 kf = *(const bf16x8*)&(KB)[(quad * 64 + st * 16 + col) * 8]; \
      const f32x4 s0 = __builtin_amdgcn_mfma_f32_16x16x32_bf16(kf, qf0, fz, 0, 0, 0); \
      const f32x4 s1 = __builtin_amdgcn_mfma_f32_16x16x32_bf16(kf, qf1, fz, 0, 0, 0); \
      (PN0)[st * 2]     = pack2bf(fast_exp2(s0[0]), fast_exp2(s0[1]));       \
      (PN0)[st * 2 + 1] = pack2bf(fast_exp2(s0[2]), fast_exp2(s0[3]));       \
      (PN1)[st * 2]     = pack2bf(fast_exp2(s1[0]), fast_exp2(s1[1]));       \
      (PN1)[st * 2 + 1] = pack2bf(fast_exp2(s1[2]), fast_exp2(s1[3]));       \
    } } while (0)

#define PV_PHASE(VB, PC0, PC1) do {                                          \
    _Pragma("unroll")                                                        \
    for (int kh = 0; kh < 2; ++kh) {                                         \
      const bf16x8 pf0 = mk8((PC0)[kh*4], (PC0)[kh*4+1], (PC0)[kh*4+2], (PC0)[kh*4+3]); \
      const bf16x8 pf1 = mk8((PC1)[kh*4], (PC1)[kh*4+1], (PC1)[kh*4+2], (PC1)[kh*4+3]); \
      _Pragma("unroll")                                                      \
      for (int hh = 0; hh < 2; ++hh) {                                       \
        const int hd = hh * 16 + col;                                        \
        const bf16x8 vf = *(const bf16x8*)&(VB)[hd * AKT + (((kh * 4 + quad) ^ (hd & 7)) * 8)]; \
        o[0][hh] = __builtin_amdgcn_mfma_f32_16x16x32_bf16(pf0, vf, o[0][hh], 0, 0, 0); \
        o[1][hh] = __builtin_amdgcn_mfma_f32_16x16x32_bf16(pf1, vf, o[1][hh], 0, 0, 0); \
      }                                                                      \
      lacc[0] = __builtin_amdgcn_mfma_f32_16x16x32_bf16(pf0, ones, lacc[0], 0, 0, 0); \
      lacc[1] = __builtin_amdgcn_mfma_f32_16x16x32_bf16(pf1, ones, lacc[1], 0, 0, 0); \
    } } while (0)

#define AITER(t_, PC0, PC1, PN0, PN1) do {                                   \
    const int vnx = (vc >= 1) ? vc - 1 : 2;     /* (vc+2)%3 */               \
    if ((t_) + 2 < NKT)                                                      \
      gload16(ksrc + (size_t)((t_) + 2) * AKT * 768, &Kbuf[(t_) & 1][tid * 8]); \
    if ((t_) + 1 < NKT) S_PHASE(Kbuf[((t_) + 1) & 1], PN0, PN1);             \
    PV_PHASE(Vbuf[vc], PC0, PC1);                                            \
    if ((t_) + 2 < NKT) {                                                    \
      _Pragma("unroll")                                                      \
      for (int j = 0; j < 8; ++j)                                            \
        Vbuf[vnx][(vhg * 8 + j) * 64 + ((vgs ^ j) * 8) + vo8] = vreg[j];     \
      if ((t_) + 3 < NKT)                                                    \
        vreg = *(const bf16x8*)(vsrc + (size_t)((t_) + 3) * AKT * 768);      \
    }                                                                        \
    __syncthreads();                                                         \
    vc = (vc == 2) ? 0 : vc + 1;                                             \
  } while (0)

  // prologue: stage K0,K1 (DMA), V0,V1 (reg+ds_write), prefetch V2 to regs
  gload16(ksrc, &Kbuf[0][tid * 8]);
  gload16(ksrc + (size_t)AKT * 768, &Kbuf[1][tid * 8]);
  {
    const bf16x8 v0 = *(const bf16x8*)vsrc;
    const bf16x8 v1 = *(const bf16x8*)(vsrc + (size_t)AKT * 768);
#pragma unroll
    for (int j = 0; j < 8; ++j) {
      Vbuf[0][(vhg * 8 + j) * 64 + ((vgs ^ j) * 8) + vo8] = v0[j];
      Vbuf[1][(vhg * 8 + j) * 64 + ((vgs ^ j) * 8) + vo8] = v1[j];
    }
  }
  bf16x8 vreg = *(const bf16x8*)(vsrc + (size_t)2 * AKT * 768);
  __syncthreads();

  uint32_t pwA0[8], pwA1[8], pwB0[8], pwB1[8];
  S_PHASE(Kbuf[0], pwA0, pwA1);    // pw for tile 0
  __syncthreads();   // iter-0's K(2) DMA targets Kbuf[0]; all waves must
                     // finish the prologue S(0) reads first.

  int vc = 0;
  for (int t = 0; t < NKT; t += 2) {
    AITER(t,     pwA0, pwA1, pwB0, pwB1);
    AITER(t + 1, pwB0, pwB1, pwA0, pwA1);
  }
#undef AITER
#undef PV_PHASE
#undef S_PHASE

  // ---- diagonal self-key (elementwise: p_self * V[q]) for test-query blocks
  if (blockIdx.x >= SPLITN / 128) {
#pragma unroll
    for (int qsub = 0; qsub < 2; ++qsub) {
      const int qd = q0 + qsub * 16;
      const bf16x8 qf = qsub ? qf1 : qf0;
      const bf16x8 kf = *(const bf16x8*)(kbase + (size_t)(qd + col) * 768 + quad * 8);
      const f32x4 sd = __builtin_amdgcn_mfma_f32_16x16x32_bf16(kf, qf, fz, 0, 0, 0);
      // diagonal element for query=col lives at lane quad==col>>2, r==col&3
      float ps = 0.f;
#pragma unroll
      for (int r = 0; r < 4; ++r)
        if (quad * 4 + r == col) ps = fast_exp2(sd[r]);
      if (quad == (col >> 2)) Pdiag[wave][col] = ps;
      asm volatile("s_waitcnt lgkmcnt(0)" ::: "memory");
      const f32x4 pv = *(const f32x4*)&Pdiag[wave][quad * 4];  // broadcast
#pragma unroll
      for (int r = 0; r < 4; ++r) {
        lacc[qsub][r] += pv[r];
        const size_t vrow = (size_t)(qd + quad * 4 + r) * 768;
#pragma unroll
        for (int hh = 0; hh < 2; ++hh)
          o[qsub][hh][r] += pv[r] * bf2f(vcol[vrow + hh * 16 + col]);
      }
      asm volatile("s_waitcnt lgkmcnt(0)" ::: "memory");  // before qsub1 rewrite
    }
  }

  // ---- epilogue: normalize in-register, write bf16 O directly
#pragma unroll
  for (int qsub = 0; qsub < 2; ++qsub) {
#pragma unroll
    for (int r = 0; r < 4; ++r) {
      const float inv = 1.0f / lacc[qsub][r];
      const size_t row = (size_t)b * TSEQ + q0 + qsub * 16 + quad * 4 + r;
#pragma unroll
      for (int hh = 0; hh < 2; ++hh)
        ob[row * DIM + h * HDIM + hh * 16 + col] = f2bf(o[qsub][hh][r] * inv);
    }
  }
}

// ------------------------------------------------------------------ launch
extern "C" void kernel_launch(void* const* d_in, const int* in_sizes, int n_in,
                              void* d_out, int out_size, void* d_ws, size_t ws_size,
                              hipStream_t stream)
{
  const float* rows = (const float*)d_in[0];
  const float* tte  = (const float*)d_in[1];
  const float* Wq = (const float*)d_in[2];  const float* bq = (const float*)d_in[3];
  const float* Wk = (const float*)d_in[4];  const float* bk = (const float*)d_in[5];
  const float* Wv = (const float*)d_in[6];  const float* bv = (const float*)d_in[7];
  const float* Wo = (const float*)d_in[8];  const float* bo = (const float*)d_in[9];
  const float* W1 = (const float*)d_in[10]; const float* b1 = (const float*)d_in[11];
  const float* W2 = (const float*)d_in[12]; const float* b2 = (const float*)d_in[13];
  const float* ln1s = (const float*)d_in[14]; const float* ln1b = (const float*)d_in[15];
  const float* ln2s = (const float*)d_in[16]; const float* ln2b = (const float*)d_in[17];

  char* p = (char*)d_ws;
  float* xf   = (float*)p;  p += (size_t)MROWS * DIM * 4;
  short* xb   = (short*)p;  p += (size_t)MROWS * DIM * 2;
  short* qkv  = (short*)p;  p += (size_t)MROWS * 768 * 2;
  short* hb   = (short*)p;  p += (size_t)MROWS * FFDIM * 2;
  short* ob   = (short*)p;  p += (size_t)MROWS * DIM * 2;
  short* qkvT = (short*)p;  p += (size_t)NLAYER * 768 * DIM * 2;
  short* woT  = (short*)p;  p += (size_t)NLAYER * DIM * DIM * 2;
  short* w1T  = (short*)p;  p += (size_t)NLAYER * FFDIM * DIM * 2;
  short* w2T  = (short*)p;  p += (size_t)NLAYER * DIM * FFDIM * 2;

  prep_w<<<2048, 256, 0, stream>>>(Wq, Wk, Wv, Wo, W1, W2, qkvT, woT, w1T, w2T);
  prep_x<<<MROWS * DIM / 4 / 256, 256, 0, stream>>>(rows, tte, xf, xb);

  for (int l = 0; l < NLAYER; ++l) {
    gemm_bt<1><<<dim3(MROWS / GBM, 768 / GBN), 256, 0, stream>>>(
        xb, qkvT + (size_t)l * 768 * DIM, bq + l * DIM, bk + l * DIM, bv + l * DIM,
        qkv, MROWS, 768, DIM);
    attn_kernel<<<dim3(TSEQ / 128, BATCH * NHEAD), 256, 0, stream>>>(qkv, ob);
    gemm_ln<<<MROWS / 16, 256, 0, stream>>>(
        ob, woT + (size_t)l * DIM * DIM, bo + l * DIM, xf,
        ln1s + l * DIM, ln1b + l * DIM, xf, xb, DIM);
    gemm_bt<3><<<dim3(MROWS / GBM, FFDIM / GBN), 256, 0, stream>>>(
        xb, w1T + (size_t)l * FFDIM * DIM, b1 + l * FFDIM, nullptr, nullptr,
        hb, MROWS, FFDIM, DIM);
    float* xo = (l == NLAYER - 1) ? (float*)d_out : xf;
    gemm_ln<<<MROWS / 16, 256, 0, stream>>>(
        hb, w2T + (size_t)l * DIM * FFDIM,
        b2 + l * DIM, xf, ln2s + l * DIM, ln2b + l * DIM, xo, xb, FFDIM);
  }
}

// Round 14
// 449.948 us; speedup vs baseline: 1.0704x; 1.0704x over previous
//
#include <hip/hip_runtime.h>
#include <cstdint>
#include <cstddef>

#define TSEQ 4096
#define BATCH 2
#define DIM 256
#define NHEAD 8
#define HDIM 32
#define NLAYER 4
#define FFDIM 1024
#define SPLITN 2048
#define MROWS (BATCH * TSEQ)   // 8192

// (1/sqrt(HD)) * log2(e)  -- folded into q at the QKV epilogue so softmax uses exp2 directly
#define QSCALE 0.2550784545f

typedef __attribute__((ext_vector_type(4))) float f32x4;
typedef __attribute__((ext_vector_type(8))) short bf16x8;

__device__ __forceinline__ short f2bf(float f) {
  union { float f; uint32_t u; } v; v.f = f;
  uint32_t r = v.u + 0x7fffu + ((v.u >> 16) & 1u);
  return (short)(r >> 16);
}

__device__ __forceinline__ float bf2f(short s) {
  union { uint32_t u; float f; } v; v.u = ((uint32_t)(uint16_t)s) << 16;
  return v.f;
}

__device__ __forceinline__ float fast_exp2(float x) {
#if __has_builtin(__builtin_amdgcn_exp2f)
  return __builtin_amdgcn_exp2f(x);
#else
  float r;
  asm volatile("v_exp_f32 %0, %1\n\ts_nop 1" : "=v"(r) : "v"(x));
  return r;
#endif
}

// pack two fp32 -> two bf16 (round-half-up; 3 VALU ops; verified rounds 0-5, 8-13)
__device__ __forceinline__ uint32_t pack2bf(float a, float b) {
  union { float f; uint32_t u; } ua, ub; ua.f = a; ub.f = b;
  return ((ua.u + 0x8000u) >> 16) | ((ub.u + 0x8000u) & 0xffff0000u);
}

__device__ __forceinline__ bf16x8 mk8(uint32_t a, uint32_t b, uint32_t c, uint32_t d) {
  union { uint32_t u[4]; bf16x8 v; } x; x.u[0] = a; x.u[1] = b; x.u[2] = c; x.u[3] = d;
  return x.v;
}

__device__ __forceinline__ float gelu_f(float x) {
  float u = 0.7978845608f * x * (1.0f + 0.044715f * x * x);
  u = fminf(fmaxf(u, -20.f), 20.f);
  float e = fast_exp2(2.885390082f * u);   // exp(2u)
  float t = (e - 1.0f) / (e + 1.0f);
  return 0.5f * x * (1.0f + t);
}

#define AS1 __attribute__((address_space(1)))
#define AS3 __attribute__((address_space(3)))
__device__ __forceinline__ void gload16(const void* g, void* l) {
  __builtin_amdgcn_global_load_lds((AS1 void*)g, (AS3 void*)l, 16, 0, 0);
}

// ---------------------------------------------------------------- weight prep
__global__ __launch_bounds__(256) void prep_w(
    const float* __restrict__ Wq, const float* __restrict__ Wk,
    const float* __restrict__ Wv, const float* __restrict__ Wo,
    const float* __restrict__ W1, const float* __restrict__ W2,
    short* __restrict__ qkvT, short* __restrict__ woT,
    short* __restrict__ w1T, short* __restrict__ w2T)
{
  const int NQKV = NLAYER * 768 * DIM;
  const int NO   = NLAYER * DIM * DIM;
  const int NF   = NLAYER * FFDIM * DIM;
  const int total = NQKV + NO + 2 * NF;
  for (int idx = blockIdx.x * 256 + threadIdx.x; idx < total; idx += gridDim.x * 256) {
    if (idx < NQKV) {                       // qkvT[l][n:768][k:256]
      const int l = idx / (768 * DIM);
      const int rem = idx - l * 768 * DIM;
      const int n = rem >> 8, k = rem & 255;
      const float* src = (n < 256) ? Wq : ((n < 512) ? Wk : Wv);
      qkvT[idx] = f2bf(src[((size_t)l * DIM + k) * DIM + (n & 255)]);
    } else if (idx < NQKV + NO) {           // woT[l][n:256][k:256]
      const int j = idx - NQKV;
      const int l = j >> 16;
      const int rem = j & 65535;
      const int n = rem >> 8, k = rem & 255;
      woT[j] = f2bf(Wo[((size_t)l * DIM + k) * DIM + n]);
    } else if (idx < NQKV + NO + NF) {      // w1T[l][n:1024][k:256]
      const int j = idx - NQKV - NO;
      const int l = j >> 18;
      const int rem = j & 262143;
      const int n = rem >> 8, k = rem & 255;
      w1T[j] = f2bf(W1[((size_t)l * DIM + k) * FFDIM + n]);
    } else {                                // w2T[l][n:256][k:1024]
      const int j = idx - NQKV - NO - NF;
      const int l = j >> 18;
      const int rem = j & 262143;
      const int n = rem >> 10, k = rem & 1023;
      w2T[j] = f2bf(W2[((size_t)l * FFDIM + k) * DIM + n]);
    }
  }
}

// ------------------------------------------------------------------- x prep
__global__ __launch_bounds__(256) void prep_x(
    const float* __restrict__ rows, const float* __restrict__ tte,
    float* __restrict__ xf, short* __restrict__ xb)
{
  const size_t idx = (size_t)blockIdx.x * 256 + threadIdx.x;  // float4 index
  float4 v = ((const float4*)rows)[idx];
  const size_t e = idx * 4;
  const int m = (int)(e >> 8);
  const int d = (int)(e & 255);
  const int t = m & (TSEQ - 1);
  const int bb = m >> 12;
  if (t < SPLITN) {
    const float4 a = ((const float4*)tte)[((size_t)bb * SPLITN + t) * (DIM / 4) + (d >> 2)];
    v.x += a.x; v.y += a.y; v.z += a.z; v.w += a.w;
  }
  ((float4*)xf)[idx] = v;
  short4 pk; pk.x = f2bf(v.x); pk.y = f2bf(v.y); pk.z = f2bf(v.z); pk.w = f2bf(v.w);
  ((short4*)xb)[idx] = pk;
}

// ---------------------------------------------------------------------- GEMM
// (m97 pattern + T2 both-sides swizzle; round-1/5 config — best measured)
// EPI: 1=qkv (+bias, q scaled, bf16)  3=gelu bf16.
#define GBM 128
#define GBN 64
#define GBK 64

template<int EPI>
__global__ __launch_bounds__(256, 4) void gemm_bt(
    const short* __restrict__ A, const short* __restrict__ BT,
    const float* __restrict__ bias0, const float* __restrict__ bias1,
    const float* __restrict__ bias2, void* __restrict__ Cout,
    int M, int N, int K)
{
  __shared__ short As[GBM * GBK];
  __shared__ short Bs[GBN * GBK];
  const int tid = threadIdx.x;
  const int lane = tid & 63;
  const int wave = tid >> 6;
  const int wm = wave & 1, wn = wave >> 1;
  const int col = lane & 15, quad = lane >> 4;

  const short* Ab = A + (size_t)blockIdx.x * GBM * K;
  const short* Bb = BT + (size_t)blockIdx.y * GBN * K;

  const f32x4 fz = {0.f, 0.f, 0.f, 0.f};
  f32x4 acc[4][2];
#pragma unroll
  for (int i = 0; i < 4; ++i)
#pragma unroll
    for (int j = 0; j < 2; ++j) acc[i][j] = fz;

  for (int k0 = 0; k0 < K; k0 += GBK) {
#pragma unroll
    for (int p = 0; p < 4; ++p) {
      const int i = p * 256 + tid;
      const int r = i >> 3, g = i & 7;
      gload16(Ab + (size_t)r * K + k0 + ((g ^ (r & 7)) * 8), &As[i * 8]);
    }
#pragma unroll
    for (int p = 0; p < 2; ++p) {
      const int i = p * 256 + tid;
      const int r = i >> 3, g = i & 7;
      gload16(Bb + (size_t)r * K + k0 + ((g ^ (r & 7)) * 8), &Bs[i * 8]);
    }
    __syncthreads();
#pragma unroll
    for (int ks = 0; ks < GBK; ks += 32) {
      bf16x8 af[4], bfr[2];
      const int gq = (ks >> 3) + quad;
#pragma unroll
      for (int tm = 0; tm < 4; ++tm) {
        const int row = wm * 64 + tm * 16 + col;
        af[tm] = *(const bf16x8*)&As[row * GBK + ((gq ^ (row & 7)) * 8)];
      }
#pragma unroll
      for (int tn = 0; tn < 2; ++tn) {
        const int row = wn * 32 + tn * 16 + col;
        bfr[tn] = *(const bf16x8*)&Bs[row * GBK + ((gq ^ (row & 7)) * 8)];
      }
#pragma unroll
      for (int tm = 0; tm < 4; ++tm)
#pragma unroll
        for (int tn = 0; tn < 2; ++tn)
          acc[tm][tn] = __builtin_amdgcn_mfma_f32_16x16x32_bf16(af[tm], bfr[tn], acc[tm][tn], 0, 0, 0);
    }
    __syncthreads();
  }

#pragma unroll
  for (int tm = 0; tm < 4; ++tm) {
    const int mbase = blockIdx.x * GBM + wm * 64 + tm * 16 + quad * 4;
#pragma unroll
    for (int tn = 0; tn < 2; ++tn) {
      const int n = blockIdx.y * GBN + wn * 32 + tn * 16 + col;
      float bv;
      if (EPI == 1) bv = (n < 256) ? bias0[n] : ((n < 512) ? bias1[n - 256] : bias2[n - 512]);
      else          bv = bias0[n];
#pragma unroll
      for (int r = 0; r < 4; ++r) {
        float v = acc[tm][tn][r] + bv;
        size_t off = (size_t)(mbase + r) * N + n;
        if (EPI == 1) {
          if (n < 256) v *= QSCALE;
          ((short*)Cout)[off] = f2bf(v);
        } else {
          ((short*)Cout)[off] = f2bf(gelu_f(v));
        }
      }
    }
  }
}

// ------------------------------------------------ GEMM + residual + LN fused
// C = A@BT^T + bias (N=256 full), out = LN(xres + C)*gs + gb.
// M-tile 16, grid 512 = 2 blocks/CU (round-11 win: was 1 wave/SIMD at M32).
__global__ __launch_bounds__(256, 2) void gemm_ln(
    const short* __restrict__ A,
    const short* __restrict__ BT, const float* __restrict__ bias,
    const float* __restrict__ xres,
    const float* __restrict__ gs, const float* __restrict__ gb,
    float* __restrict__ xoutf, short* __restrict__ xoutb, int K)
{
  __shared__ short As[2][16 * 64];
  __shared__ short Bs[2][256 * 64];
  __shared__ float ssum[4][16], ssq[4][16];
  const int tid = threadIdx.x;
  const int lane = tid & 63;
  const int wave = tid >> 6;
  const int col = lane & 15, quad = lane >> 4;
  const int m0 = blockIdx.x * 16;

  const f32x4 fz = {0.f, 0.f, 0.f, 0.f};
  f32x4 acc[4];
#pragma unroll
  for (int j = 0; j < 4; ++j) acc[j] = fz;

  // per-thread A-staging coords: 128 granules (16 rows x 8), threads <128
  const int arow = (tid >> 3) & 15;   // 0..15
  const int agr  = tid & 7;           // granule (8 cols)
  const int grow = m0 + arow;
  const int asw  = (agr ^ (arow & 7)) * 8;   // swizzled source granule (elems)

#define STAGE_B(k0_, buf_) do {                                              \
    _Pragma("unroll")                                                        \
    for (int p_ = 0; p_ < 8; ++p_) {                                         \
      const int i_ = p_ * 256 + tid;                                         \
      const int r_ = i_ >> 3, g_ = i_ & 7;                                   \
      gload16(BT + (size_t)r_ * K + (k0_) + ((g_ ^ (r_ & 7)) * 8),           \
              &Bs[buf_][i_ * 8]);                                            \
    } } while (0)

#define STAGE_A(k0_, buf_) do {                                              \
    if (tid < 128)                                                           \
      gload16(A + (size_t)grow * K + (k0_) + asw, &As[buf_][tid * 8]);       \
    } while (0)

  const int NT = K / 64;
  STAGE_B(0, 0);
  STAGE_A(0, 0);
  __syncthreads();

  int cur = 0;
  for (int t = 0; t < NT; ++t) {
    if (t + 1 < NT) {
      STAGE_B((t + 1) * 64, cur ^ 1);
      STAGE_A((t + 1) * 64, cur ^ 1);
    }
#pragma unroll
    for (int ks = 0; ks < 64; ks += 32) {
      bf16x8 af, bfr[4];
      const int gq = (ks >> 3) + quad;
      af = *(const bf16x8*)&As[cur][col * 64 + ((gq ^ (col & 7)) * 8)];
#pragma unroll
      for (int tn = 0; tn < 4; ++tn) {
        const int row = wave * 64 + tn * 16 + col;
        bfr[tn] = *(const bf16x8*)&Bs[cur][row * 64 + ((gq ^ (row & 7)) * 8)];
      }
#pragma unroll
      for (int tn = 0; tn < 4; ++tn)
        acc[tn] = __builtin_amdgcn_mfma_f32_16x16x32_bf16(af, bfr[tn], acc[tn], 0, 0, 0);
    }
    __syncthreads();
    cur ^= 1;
  }
#undef STAGE_B
#undef STAGE_A

  // v = acc + bias + residual
  const float* resb = xres + (size_t)m0 * DIM;
#pragma unroll
  for (int tn = 0; tn < 4; ++tn) {
    const int n = wave * 64 + tn * 16 + col;
    const float bv = bias[n];
#pragma unroll
    for (int r = 0; r < 4; ++r) {
      const int row = quad * 4 + r;
      acc[tn][r] += bv + resb[(size_t)row * DIM + n];
    }
  }

  // per-row LN stats (rows 0..15)
#pragma unroll
  for (int r = 0; r < 4; ++r) {
    float s = 0.f, q = 0.f;
#pragma unroll
    for (int tn = 0; tn < 4; ++tn) { const float v = acc[tn][r]; s += v; q += v * v; }
    s += __shfl_xor(s, 1); q += __shfl_xor(q, 1);
    s += __shfl_xor(s, 2); q += __shfl_xor(q, 2);
    s += __shfl_xor(s, 4); q += __shfl_xor(q, 4);
    s += __shfl_xor(s, 8); q += __shfl_xor(q, 8);
    if (col == 0) { const int row = quad * 4 + r; ssum[wave][row] = s; ssq[wave][row] = q; }
  }
  __syncthreads();
  if (tid < 16) {
    const float S = ssum[0][tid] + ssum[1][tid] + ssum[2][tid] + ssum[3][tid];
    const float Q = ssq[0][tid] + ssq[1][tid] + ssq[2][tid] + ssq[3][tid];
    const float mu = S * (1.0f / DIM);
    const float var = Q * (1.0f / DIM) - mu * mu;
    ssum[0][tid] = mu;
    ssq[0][tid] = rsqrtf(var + 1e-5f);
  }
  __syncthreads();

#pragma unroll
  for (int tn = 0; tn < 4; ++tn) {
    const int n = wave * 64 + tn * 16 + col;
    const float g = gs[n], bb = gb[n];
#pragma unroll
    for (int r = 0; r < 4; ++r) {
      const int row = quad * 4 + r;
      const float out = (acc[tn][r] - ssum[0][row]) * ssq[0][row] * g + bb;
      xoutf[(size_t)(m0 + row) * DIM + n] = out;
      xoutb[(size_t)(m0 + row) * DIM + n] = f2bf(out);
    }
  }
}

// ----------------------------------------------------------------- attention
// Round-5 inner loop (verified best) at 8-wave / 256-query blocks: each
// staged 64-key K/V tile now serves 2x the queries (round 4 proved intensity
// halving costs +20us; this doubles it).  Staging roles split by wave:
// waves 4-7 issue the 256 K-DMAs (part=wave-4, key=lane), waves 0-3 do the
// V reg-load + swizzled ds_write (hd-group=wave, key=lane) — per-wave
// staging overhead halves too.  Grid = 256 blocks = 1 block/CU, 8 waves
// (same 2 waves/SIMD as before but correlated barriers — the measured A/B).
// K staged via global_load_lds in hd-part planes [part][key].  V staged with
// the PERMUTED key order (contraction invariant under a key permutation
// applied to both P and V):
//   slot k = quad*8+e  <->  key = (2*kh + (e>>2))*16 + quad*4 + (e&3)
// so P fragments are built entirely in registers after exp2 (no LDS P).
// Block owns the full softmax denominator -> normalize in-register, write
// bf16 O directly.  Diagonal self-key handled elementwise.
#define AKT 64
#define NKT (SPLITN / AKT)   // 32

__global__ __launch_bounds__(512, 1) void attn_kernel(
    const short* __restrict__ qkv, short* __restrict__ ob)
{
  __shared__ short Kbuf[2][AKT * HDIM];   // [part(4)][key(64)][8]
  __shared__ short Vbuf[2][HDIM * AKT];   // [hd][slot-swz], slot = permuted key
  __shared__ float Pdiag[8][16];

  const int tid = threadIdx.x;
  const int lane = tid & 63;
  const int wave = tid >> 6;              // 0..7
  const int col = lane & 15, quad = lane >> 4;
  const int bh = blockIdx.y;
  const int b = bh >> 3, h = bh & 7;
  const int q0 = blockIdx.x * 256 + wave * 32;

  const short* qbase = qkv + (size_t)b * TSEQ * 768 + h * HDIM;
  const short* kbase = qbase + 256;
  const short* vcol  = qbase + 512;

  // K staging (waves 4-7): part = wave-4, key = lane -> gload16, lane-linear
  const int kpart = wave & 3;
  const short* ksrc = kbase + (size_t)lane * 768 + kpart * 8;
  const int kdst = (kpart * 64 + lane) * 8;   // element offset in Kbuf plane
  // V staging (waves 0-3): key = lane, hd-group = wave (8 hd, 16B contiguous).
  const int vkey = lane, vhg = wave & 3;
  const int vs = vkey >> 4, vqd = (vkey >> 2) & 3, vrr = vkey & 3;
  const int vpos = (vs >> 1) * 32 + vqd * 8 + (vs & 1) * 4 + vrr;
  const int vgs = vpos >> 3, vo8 = vpos & 7;   // granule slot, in-granule offset
  const short* vsrc = vcol + (size_t)vkey * 768 + vhg * 8;

  const bf16x8 qf0 = *(const bf16x8*)(qbase + (size_t)(q0 + col) * 768 + quad * 8);
  const bf16x8 qf1 = *(const bf16x8*)(qbase + (size_t)(q0 + 16 + col) * 768 + quad * 8);

  bf16x8 ones;
#pragma unroll
  for (int i = 0; i < 8; ++i) ones[i] = (short)0x3F80;

  const f32x4 fz = {0.f, 0.f, 0.f, 0.f};
  f32x4 o[2][2] = {{fz, fz}, {fz, fz}};
  f32x4 lacc[2] = {fz, fz};

  // prologue: stage tile 0 (K via DMA by waves 4-7, V via load+ds_write by
  // waves 0-3), prefetch V tile 1 to regs (waves 0-3)
  bf16x8 vnext;
  if (wave >= 4) {
    gload16(ksrc, &Kbuf[0][kdst]);
  } else {
    const bf16x8 v0 = *(const bf16x8*)vsrc;
#pragma unroll
    for (int j = 0; j < 8; ++j)
      Vbuf[0][(vhg * 8 + j) * 64 + ((vgs ^ j) * 8) + vo8] = v0[j];
    vnext = *(const bf16x8*)(vsrc + (size_t)AKT * 768);
  }

  int cur = 0;
  for (int t = 0; t < NKT; ++t) {
    __syncthreads();
    if (t + 1 < NKT) {
      if (wave >= 4) {
        gload16(ksrc + (size_t)(t + 1) * AKT * 768, &Kbuf[1 - cur][kdst]);
      } else {
#pragma unroll
        for (int j = 0; j < 8; ++j)
          Vbuf[1 - cur][(vhg * 8 + j) * 64 + ((vgs ^ j) * 8) + vo8] = vnext[j];
        if (t + 2 < NKT) vnext = *(const bf16x8*)(vsrc + (size_t)(t + 2) * AKT * 768);
      }
    }
    const short* kb = Kbuf[cur];
    const short* vb = Vbuf[cur];

    // ---- S phase: P fragments built entirely in registers
    uint32_t pw0[8], pw1[8];
#pragma unroll
    for (int st = 0; st < 4; ++st) {
      const bf16x8 kf = *(const bf16x8*)&kb[(quad * 64 + st * 16 + col) * 8];
      const f32x4 s0 = __builtin_amdgcn_mfma_f32_16x16x32_bf16(kf, qf0, fz, 0, 0, 0);
      const f32x4 s1 = __builtin_amdgcn_mfma_f32_16x16x32_bf16(kf, qf1, fz, 0, 0, 0);
      pw0[st * 2]     = pack2bf(fast_exp2(s0[0]), fast_exp2(s0[1]));
      pw0[st * 2 + 1] = pack2bf(fast_exp2(s0[2]), fast_exp2(s0[3]));
      pw1[st * 2]     = pack2bf(fast_exp2(s1[0]), fast_exp2(s1[1]));
      pw1[st * 2 + 1] = pack2bf(fast_exp2(s1[2]), fast_exp2(s1[3]));
    }

    // ---- PV phase (P from registers, V in permuted-key order)
#pragma unroll
    for (int kh = 0; kh < 2; ++kh) {
      const bf16x8 pf0 = mk8(pw0[kh * 4], pw0[kh * 4 + 1], pw0[kh * 4 + 2], pw0[kh * 4 + 3]);
      const bf16x8 pf1 = mk8(pw1[kh * 4], pw1[kh * 4 + 1], pw1[kh * 4 + 2], pw1[kh * 4 + 3]);
#pragma unroll
      for (int hh = 0; hh < 2; ++hh) {
        const int hd = hh * 16 + col;
        const bf16x8 vf = *(const bf16x8*)&vb[hd * AKT + (((kh * 4 + quad) ^ (hd & 7)) * 8)];
        o[0][hh] = __builtin_amdgcn_mfma_f32_16x16x32_bf16(pf0, vf, o[0][hh], 0, 0, 0);
        o[1][hh] = __builtin_amdgcn_mfma_f32_16x16x32_bf16(pf1, vf, o[1][hh], 0, 0, 0);
      }
      lacc[0] = __builtin_amdgcn_mfma_f32_16x16x32_bf16(pf0, ones, lacc[0], 0, 0, 0);
      lacc[1] = __builtin_amdgcn_mfma_f32_16x16x32_bf16(pf1, ones, lacc[1], 0, 0, 0);
    }
    cur ^= 1;
  }

  // ---- diagonal self-key (elementwise: p_self * V[q]) for test-query blocks
  if (blockIdx.x >= SPLITN / 256) {
#pragma unroll
    for (int qsub = 0; qsub < 2; ++qsub) {
      const int qd = q0 + qsub * 16;
      const bf16x8 qf = qsub ? qf1 : qf0;
      const bf16x8 kf = *(const bf16x8*)(kbase + (size_t)(qd + col) * 768 + quad * 8);
      const f32x4 sd = __builtin_amdgcn_mfma_f32_16x16x32_bf16(kf, qf, fz, 0, 0, 0);
      // diagonal element for query=col lives at lane quad==col>>2, r==col&3
      float ps = 0.f;
#pragma unroll
      for (int r = 0; r < 4; ++r)
        if (quad * 4 + r == col) ps = fast_exp2(sd[r]);
      if (quad == (col >> 2)) Pdiag[wave][col] = ps;
      asm volatile("s_waitcnt lgkmcnt(0)" ::: "memory");
      const f32x4 pv = *(const f32x4*)&Pdiag[wave][quad * 4];  // broadcast
#pragma unroll
      for (int r = 0; r < 4; ++r) {
        lacc[qsub][r] += pv[r];
        const size_t vrow = (size_t)(qd + quad * 4 + r) * 768;
#pragma unroll
        for (int hh = 0; hh < 2; ++hh)
          o[qsub][hh][r] += pv[r] * bf2f(vcol[vrow + hh * 16 + col]);
      }
      asm volatile("s_waitcnt lgkmcnt(0)" ::: "memory");  // before qsub1 rewrite
    }
  }

  // ---- epilogue: normalize in-register, write bf16 O directly
#pragma unroll
  for (int qsub = 0; qsub < 2; ++qsub) {
#pragma unroll
    for (int r = 0; r < 4; ++r) {
      const float inv = 1.0f / lacc[qsub][r];
      const size_t row = (size_t)b * TSEQ + q0 + qsub * 16 + quad * 4 + r;
#pragma unroll
      for (int hh = 0; hh < 2; ++hh)
        ob[row * DIM + h * HDIM + hh * 16 + col] = f2bf(o[qsub][hh][r] * inv);
    }
  }
}

// ------------------------------------------------------------------ launch
extern "C" void kernel_launch(void* const* d_in, const int* in_sizes, int n_in,
                              void* d_out, int out_size, void* d_ws, size_t ws_size,
                              hipStream_t stream)
{
  const float* rows = (const float*)d_in[0];
  const float* tte  = (const float*)d_in[1];
  const float* Wq = (const float*)d_in[2];  const float* bq = (const float*)d_in[3];
  const float* Wk = (const float*)d_in[4];  const float* bk = (const float*)d_in[5];
  const float* Wv = (const float*)d_in[6];  const float* bv = (const float*)d_in[7];
  const float* Wo = (const float*)d_in[8];  const float* bo = (const float*)d_in[9];
  const float* W1 = (const float*)d_in[10]; const float* b1 = (const float*)d_in[11];
  const float* W2 = (const float*)d_in[12]; const float* b2 = (const float*)d_in[13];
  const float* ln1s = (const float*)d_in[14]; const float* ln1b = (const float*)d_in[15];
  const float* ln2s = (const float*)d_in[16]; const float* ln2b = (const float*)d_in[17];

  char* p = (char*)d_ws;
  float* xf   = (float*)p;  p += (size_t)MROWS * DIM * 4;
  short* xb   = (short*)p;  p += (size_t)MROWS * DIM * 2;
  short* qkv  = (short*)p;  p += (size_t)MROWS * 768 * 2;
  short* hb   = (short*)p;  p += (size_t)MROWS * FFDIM * 2;
  short* ob   = (short*)p;  p += (size_t)MROWS * DIM * 2;
  short* qkvT = (short*)p;  p += (size_t)NLAYER * 768 * DIM * 2;
  short* woT  = (short*)p;  p += (size_t)NLAYER * DIM * DIM * 2;
  short* w1T  = (short*)p;  p += (size_t)NLAYER * FFDIM * DIM * 2;
  short* w2T  = (short*)p;  p += (size_t)NLAYER * DIM * FFDIM * 2;

  prep_w<<<2048, 256, 0, stream>>>(Wq, Wk, Wv, Wo, W1, W2, qkvT, woT, w1T, w2T);
  prep_x<<<MROWS * DIM / 4 / 256, 256, 0, stream>>>(rows, tte, xf, xb);

  for (int l = 0; l < NLAYER; ++l) {
    gemm_bt<1><<<dim3(MROWS / GBM, 768 / GBN), 256, 0, stream>>>(
        xb, qkvT + (size_t)l * 768 * DIM, bq + l * DIM, bk + l * DIM, bv + l * DIM,
        qkv, MROWS, 768, DIM);
    attn_kernel<<<dim3(TSEQ / 256, BATCH * NHEAD), 512, 0, stream>>>(qkv, ob);
    gemm_ln<<<MROWS / 16, 256, 0, stream>>>(
        ob, woT + (size_t)l * DIM * DIM, bo + l * DIM, xf,
        ln1s + l * DIM, ln1b + l * DIM, xf, xb, DIM);
    gemm_bt<3><<<dim3(MROWS / GBM, FFDIM / GBN), 256, 0, stream>>>(
        xb, w1T + (size_t)l * FFDIM * DIM, b1 + l * FFDIM, nullptr, nullptr,
        hb, MROWS, FFDIM, DIM);
    float* xo = (l == NLAYER - 1) ? (float*)d_out : xf;
    gemm_ln<<<MROWS / 16, 256, 0, stream>>>(
        hb, w2T + (size_t)l * DIM * FFDIM,
        b2 + l * DIM, xf, ln2s + l * DIM, ln2b + l * DIM, xo, xb, FFDIM);
  }
}